// Round 11
// baseline (188.748 us; speedup 1.0000x reference)
//
#include <hip/hip_runtime.h>
#include <cstdint>
#include <cstddef>

// EcoAttention: block-local top-p truncated attention, S=4096 D=128 BLOCK=64.
//
// R11: barrier-free free-running waves at 32 waves/CU.
//  - K-fragments are read DIRECTLY from the prep buffer in A-frag linear
//    order (like Vt since R9) -> no LDS K staging, no __syncthreads in the
//    main loop at all. LDS = 8KB wave-private weight scratch only.
//  - 8 WG/CU (__launch_bounds__(256,8), VGPR<=64); NJG=32 -> 2048 WGs =
//    exactly 8/CU. 8 waves/SIMD hide L2 latency + sort chains.
//  - prep emits: Khi-frag | Kr-frag (f16 2-term split, frag linear order) |
//    Vt-frag. P = 3MB, L2-resident per XCD.
//  - epilogue: fire-and-forget atomicAdd over 32 j-groups.

#define SEQ   4096
#define DIM   128
#define BLK   64
#define NB    (SEQ / BLK)   // 64
#define NJG   32            // j-groups (2048 WGs)
#define JPB   (NB / NJG)    // 2 key blocks per WG
#define NT    256
#define PSTR  12288         // uints per prepped block (Khi 16KB | Kr 16KB | Vt 16KB)
#define THRESH 0.95f
#define EPSF   1e-8f

typedef __attribute__((ext_vector_type(8))) _Float16 f16x8;
typedef __attribute__((ext_vector_type(4))) float    f32x4;

#define MFMAH(a, b, c) __builtin_amdgcn_mfma_f32_16x16x32_f16((a), (b), (c), 0, 0, 0)

union UH4 { uint2 u; _Float16 h[4]; };
union UH8 { uint4 u; f16x8 v; };

// ---- prep: LDS-free, 4 WGs per key block. Emits K hi/res f16 split planes
//      in A-FRAGMENT linear order + Vt in B-fragment linear order; zeroes O.
//      Frag fi = (ks*4+quad)*64 + rB holds K[rB][ (ks*4+quad)*8 .. +8 ). ----
__global__ __launch_bounds__(NT, 4) void eco_prep_kernel(
    const float* __restrict__ K, const float* __restrict__ V,
    uint* __restrict__ P, float* __restrict__ O) {
  const int tid  = threadIdx.x;
  const int b    = blockIdx.x;     // 0..255
  const int jb   = b >> 2;
  const int part = b & 3;

  // zero O slice (2MB spread over 256 WGs)
  {
    float4 z = {0.f, 0.f, 0.f, 0.f};
    float4* op = (float4*)O;
#pragma unroll
    for (int it = 0; it < 2; ++it) op[b * 512 + it * NT + tid] = z;
  }

  // K 2-term f16 split -> frag-linear planes (1024 frags/plane per block)
  {
    const float* gk = K + (size_t)jb * BLK * DIM;
    uint4* dh = (uint4*)(P + (size_t)jb * PSTR);
    uint4* dr = (uint4*)(P + (size_t)jb * PSTR + 4096);
    int fi = part * 256 + tid;          // frag idx 0..1023
    int rB = fi & 63, kq = fi >> 6;     // kq = ks*4+quad
    const float* src = gk + rB * DIM + kq * 8;
    UH8 uh, ur;
#pragma unroll
    for (int j = 0; j < 8; ++j) {
      float v = src[j];
      _Float16 h = (_Float16)v;
      uh.v[j] = h;
      ur.v[j] = (_Float16)(v - (float)h);   // exact residual (Sterbenz)
    }
    dh[fi] = uh.u;
    dr[fi] = ur.u;
  }

  // Vt in PV B-frag linear order: frag idx = ch*128 + d (ch = c/8),
  // 8 f16 = V[ch*8+j][d].
  {
    const float* gv = V + (size_t)jb * BLK * DIM;
    uint4* dv = (uint4*)(P + (size_t)jb * PSTR + 8192);
    int idx = part * 256 + tid;            // frag idx 0..1023
    int ch = idx >> 7, d = idx & 127;
    UH8 u;
#pragma unroll
    for (int j = 0; j < 8; ++j)
      u.v[j] = (_Float16)gv[(ch * 8 + j) * DIM + d];
    dv[idx] = u.u;
  }
}

// lane-uniform-direction compare-exchange (desc if d)
#define CE(x, y, dmax) { float _hi = fmaxf((x), (y)); float _lo = fminf((x), (y)); \
                         (x) = (dmax) ? _hi : _lo; (y) = (dmax) ? _lo : _hi; }

__global__ __launch_bounds__(NT, 8) void eco_attn_kernel(
    const float* __restrict__ Q, const uint* __restrict__ P,
    float* __restrict__ O) {
  __shared__ __align__(16) uint sW[2048];   // 8 KB: 4 x (16 rows x 32 uints)

  const int tid  = threadIdx.x;
  const int ib   = blockIdx.y;
  const int jg   = blockIdx.x;
  const int lane = tid & 63;
  const int wv   = tid >> 6;
  const int quad = lane >> 4;   // 0..3
  const int l16  = lane & 15;
  const int q4   = quad << 2;

  uint* sWw = sW + wv * 512;    // this wave's weight rows (16 x 32 uints)

  // ---- Q fragments (B-operand): q-row = wv*16+l16, k = ks*32+quad*8+j ----
  f16x8 qh[4], qr[4];
  {
    const float* qp = Q + (size_t)(ib * BLK + wv * 16 + l16) * DIM + quad * 8;
#pragma unroll
    for (int ks = 0; ks < 4; ++ks) {
      float4 x0 = *(const float4*)(qp + ks * 32);
      float4 x1 = *(const float4*)(qp + ks * 32 + 4);
      float xs[8] = {x0.x, x0.y, x0.z, x0.w, x1.x, x1.y, x1.z, x1.w};
      f16x8 h8, r8;
#pragma unroll
      for (int e = 0; e < 8; ++e) {
        float v = xs[e];
        _Float16 h = (_Float16)v;
        h8[e] = h;
        r8[e] = (_Float16)(v - (float)h);
      }
      qh[ks] = h8; qr[ks] = r8;
    }
  }

  const f32x4 zf = {0.f, 0.f, 0.f, 0.f};
  f32x4 pv[8];
#pragma unroll
  for (int i = 0; i < 8; ++i) pv[i] = zf;

  for (int jj = 0; jj < JPB; ++jj) {
    const int jb = jg * JPB + jj;
    const uint* kf  = P + (size_t)jb * PSTR;         // Khi frags
    const uint* kfr = kf + 4096;                     // Kr frags
    const uint* gvt = kf + 8192;                     // Vt frags

    // ---- QK^T, operand-swapped: A = K frags (global/L2), B = Q (resident) ----
    // C: col(l16) = Q-row (wv*16+l16), row(quad*4+reg) = K-row nt*16+quad*4+reg
    f32x4 ah[4], ar[4];
#pragma unroll
    for (int nt = 0; nt < 4; ++nt) { ah[nt] = zf; ar[nt] = zf; }
#pragma unroll
    for (int nt = 0; nt < 4; ++nt) {
#pragma unroll
      for (int ks = 0; ks < 4; ++ks) {
        uint fi = ((uint)((ks * 4 + quad) * 64 + nt * 16 + l16)) << 2;
        f16x8 bh = *(const f16x8*)&kf[fi];
        f16x8 br = *(const f16x8*)&kfr[fi];
        ah[nt] = MFMAH(bh, qh[ks], ah[nt]);
        ar[nt] = MFMAH(br, qh[ks], ar[nt]);
        ar[nt] = MFMAH(bh, qr[ks], ar[nt]);
      }
    }

    // ---- top-p softmax, register-direct: this lane owns Q-row wv*16+l16;
    //      a[i] (i = nt*4+rg) is score at K-index nt*16 + q4 + rg ----
    {
      float a[16], e[16];
#pragma unroll
      for (int nt = 0; nt < 4; ++nt) {
        f32x4 s = ah[nt] + ar[nt];
#pragma unroll
        for (int rg = 0; rg < 4; ++rg) a[nt * 4 + rg] = s[rg];
      }
      // row max: local tree + cross-quad (lanes l16, +16, +32, +48)
      float mt[8];
#pragma unroll
      for (int i = 0; i < 8; ++i) mt[i] = fmaxf(a[i], a[i + 8]);
#pragma unroll
      for (int w2 = 4; w2 >= 1; w2 >>= 1)
#pragma unroll
        for (int i = 0; i < w2; ++i) mt[i] = fmaxf(mt[i], mt[i + w2]);
      float m = mt[0];
      m = fmaxf(m, __shfl_xor(m, 16, 64));
      m = fmaxf(m, __shfl_xor(m, 32, 64));
#pragma unroll
      for (int i = 0; i < 16; ++i) { a[i] = __expf(a[i] - m); e[i] = a[i]; }
      float st[8];
#pragma unroll
      for (int i = 0; i < 8; ++i) st[i] = a[i] + a[i + 8];
#pragma unroll
      for (int w2 = 4; w2 >= 1; w2 >>= 1)
#pragma unroll
        for (int i = 0; i < w2; ++i) st[i] += st[i + w2];
      float sr = st[0];
      sr += __shfl_xor(sr, 16, 64);
      sr += __shfl_xor(sr, 32, 64);
      const float T = THRESH * sr;

      // bitonic sort DESC over 64 = 4 quad-lanes x 16 regs (value-sort)
      const int s = quad;
#pragma unroll
      for (int k2 = 2; k2 <= 8; k2 <<= 1)
#pragma unroll
        for (int j2 = k2 >> 1; j2 >= 1; j2 >>= 1)
#pragma unroll
          for (int i = 0; i < 16; ++i) {
            int l = i ^ j2;
            if (l > i) { bool d = ((i & k2) == 0); CE(a[i], a[l], d); }
          }
      const bool x16 = ((s & 1) == 0);
      const bool x32 = ((s & 2) == 0);
#pragma unroll
      for (int j2 = 8; j2 >= 1; j2 >>= 1)
#pragma unroll
        for (int i = 0; i < 16; ++i) {
          int l = i ^ j2;
          if (l > i) { CE(a[i], a[l], x16); }
        }
      {
        const bool km = (x32 == x16);
#pragma unroll
        for (int i = 0; i < 16; ++i) {
          float o = __shfl_xor(a[i], 16, 64);
          a[i] = km ? fmaxf(a[i], o) : fminf(a[i], o);
        }
#pragma unroll
        for (int j2 = 8; j2 >= 1; j2 >>= 1)
#pragma unroll
          for (int i = 0; i < 16; ++i) {
            int l = i ^ j2;
            if (l > i) { CE(a[i], a[l], x32); }
          }
      }
      {
#pragma unroll
        for (int i = 0; i < 16; ++i) {
          float o = __shfl_xor(a[i], 32, 64);
          a[i] = x32 ? fmaxf(a[i], o) : fminf(a[i], o);
        }
#pragma unroll
        for (int i = 0; i < 16; ++i) {
          float o = __shfl_xor(a[i], 16, 64);
          a[i] = x16 ? fmaxf(a[i], o) : fminf(a[i], o);
        }
#pragma unroll
        for (int j2 = 8; j2 >= 1; j2 >>= 1)
#pragma unroll
          for (int i = 0; i < 16; ++i) {
            int l = i ^ j2;
            if (l > i) { CE(a[i], a[l], true); }
          }
      }
      // global inclusive cumsum, count t
#pragma unroll
      for (int i = 1; i < 16; ++i) a[i] += a[i - 1];
      float tot = a[15];
      float c = tot;
      float o1 = __shfl_up(c, 16, 64); if (s >= 1) c += o1;
      float o2 = __shfl_up(c, 32, 64); if (s >= 2) c += o2;
      const float excl = c - tot;
      int cnt = 0;
#pragma unroll
      for (int i = 0; i < 16; ++i) cnt += ((a[i] + excl) < T) ? 1 : 0;
      cnt += __shfl_xor(cnt, 16, 64);
      cnt += __shfl_xor(cnt, 32, 64);
      const int t = cnt;
      // renormalize first-t (ORIGINAL K order; kidx = nt*16 + q4 + rg)
      float p = 0.f;
#pragma unroll
      for (int i = 0; i < 16; ++i) {
        int kidx = ((i >> 2) << 4) + q4 + (i & 3);
        p += (kidx < t) ? e[i] : 0.f;
      }
      p += __shfl_xor(p, 16, 64);
      p += __shfl_xor(p, 32, 64);
      const float rn = 1.0f / (p + EPSF);
      // emit f16 weights: row l16, 16 chunks of 4 f16; chunk c4 = nt*4+quad
      // at swizzled uint offset row*32 + ((c4 ^ row) << 1)
      uint* wrow = sWw + l16 * 32;
#pragma unroll
      for (int nt = 0; nt < 4; ++nt) {
        UH4 u;
#pragma unroll
        for (int rg = 0; rg < 4; ++rg) {
          int kidx = nt * 16 + q4 + rg;
          float w = (kidx < t) ? e[nt * 4 + rg] * rn : 0.f;
          u.h[rg] = (_Float16)w;
        }
        uint c4 = (uint)(nt * 4 + quad);
        *(uint2*)&wrow[(c4 ^ (uint)l16) << 1] = u.u;
      }
    }
    __builtin_amdgcn_wave_barrier();  // weight writes before A-frag reads

    // ---- PV: A = f16 weights (wave-private LDS), B = Vt-frag from global ----
    f16x8 wf[2];
#pragma unroll
    for (int ks2 = 0; ks2 < 2; ++ks2) {
      uint c0 = (uint)(ks2 * 8 + quad * 2);
      const uint* wrow = sWw + l16 * 32;
      uint2 lo = *(const uint2*)&wrow[(c0 ^ (uint)l16) << 1];
      uint2 hi = *(const uint2*)&wrow[((c0 + 1) ^ (uint)l16) << 1];
      UH8 u;
      u.u = make_uint4(lo.x, lo.y, hi.x, hi.y);
      wf[ks2] = u.v;
    }
#pragma unroll
    for (int nt2 = 0; nt2 < 8; ++nt2) {
#pragma unroll
      for (int ks2 = 0; ks2 < 2; ++ks2) {
        f16x8 vf = *(const f16x8*)&gvt[((uint)((ks2 * 4 + quad) * 128 +
                                               nt2 * 16 + l16)) << 2];
        pv[nt2] = MFMAH(wf[ks2], vf, pv[nt2]);
      }
    }
    __builtin_amdgcn_wave_barrier();  // PV weight reads before next-iter writes
  }

  // ---- epilogue: C-layout -> global atomicAdd over the 32 j-groups ----
#pragma unroll
  for (int nt2 = 0; nt2 < 8; ++nt2) {
    const int col  = nt2 * 16 + l16;
    const int row0 = ib * BLK + wv * 16 + quad * 4;
#pragma unroll
    for (int rg = 0; rg < 4; ++rg)
      atomicAdd(O + (size_t)(row0 + rg) * DIM + col, pv[nt2][rg]);
  }
}

extern "C" void kernel_launch(void* const* d_in, const int* in_sizes, int n_in,
                              void* d_out, int out_size, void* d_ws, size_t ws_size,
                              hipStream_t stream) {
  (void)in_sizes; (void)n_in; (void)ws_size; (void)out_size;
  const float* q = (const float*)d_in[0];
  const float* k = (const float*)d_in[1];
  const float* v = (const float*)d_in[2];
  float* out = (float*)d_out;
  uint* prep = (uint*)d_ws;   // 64 blocks x 48 KB = 3 MB

  eco_prep_kernel<<<dim3(NB * 4), dim3(NT), 0, stream>>>(k, v, prep, out);
  eco_attn_kernel<<<dim3(NJG, NB), dim3(NT), 0, stream>>>(q, prep, out);
}

// Round 12
// 121.150 us; speedup vs baseline: 1.5580x; 1.5580x over previous
//
#include <hip/hip_runtime.h>
#include <cstdint>
#include <cstddef>

// EcoAttention: block-local top-p truncated attention, S=4096 D=128 BLOCK=64.
//
// R12 = R10 structure (LDS K staging, 4 WG/CU — R11 proved staging is the
//       L2-traffic deduplicator; direct per-wave K reads blew FETCH to 185MB)
//       + top-p via ITERATIVE MAX-EXTRACTION instead of a full bitonic sort:
//       t = #extraction steps with running descending sum < 0.95*S. Scores
//       are exp-dominated (t is 1-4 typically): 4 unrolled steps + rare tail
//       loop. ~56 VALU/step vs ~830 VALU for the sort -> cuts the dominant
//       VALU consumer ~3x. Extraction order == reference sorted-cumsum.

#define SEQ   4096
#define DIM   128
#define BLK   64
#define NB    (SEQ / BLK)   // 64
#define NJG   16            // j-groups (1024 WGs)
#define JPB   (NB / NJG)    // 4 key blocks per WG
#define NT    256
#define PSTR  12288         // uints per prepped block (Khi 16KB | Kr 16KB | Vt 16KB)
#define THRESH 0.95f
#define EPSF   1e-8f

typedef __attribute__((ext_vector_type(8))) _Float16 f16x8;
typedef __attribute__((ext_vector_type(4))) float    f32x4;

#define MFMAH(a, b, c) __builtin_amdgcn_mfma_f32_16x16x32_f16((a), (b), (c), 0, 0, 0)

union UH4 { uint2 u; _Float16 h[4]; };
union UH8 { uint4 u; f16x8 v; };

__device__ __forceinline__ void gll16(const uint* g, uint* l) {
  __builtin_amdgcn_global_load_lds(
      (const __attribute__((address_space(1))) void*)g,
      (__attribute__((address_space(3))) void*)l, 16, 0, 0);
}

// one top-p extraction step over a 64-wide row held as 4 quad-lanes x 16 regs
__device__ __forceinline__ void ext_step(float (&w)[16], float& R, int& c,
                                         bool& done, float T) {
  float lt[8];
#pragma unroll
  for (int i = 0; i < 8; ++i) lt[i] = fmaxf(w[i], w[i + 8]);
#pragma unroll
  for (int w2 = 4; w2 >= 1; w2 >>= 1)
#pragma unroll
    for (int i = 0; i < w2; ++i) lt[i] = fmaxf(lt[i], lt[i + w2]);
  const float lm = lt[0];
  float v = fmaxf(lm, __shfl_xor(lm, 16, 64));
  v = fmaxf(v, __shfl_xor(v, 32, 64));
  const float cum = R + v;
  const bool take = (!done) && (cum < T);
  c += take ? 1 : 0;
  // remove the extracted max (exp values > 0; -1 acts as -inf). Bit-equal
  // duplicates across lanes are measure-zero; accept the tie-break.
  if ((!done) && (lm == v)) {
#pragma unroll
    for (int i = 0; i < 16; ++i) w[i] = (w[i] == v) ? -1.0f : w[i];
  }
  R = done ? R : cum;
  done = done || (cum >= T);
}

// ---- prep: LDS-free, 4 WGs per key block. Builds [Khi|Kr|Vt-frag] 48KB
//      images in d_ws and zeroes O. ----
__global__ __launch_bounds__(NT, 4) void eco_prep_kernel(
    const float* __restrict__ K, const float* __restrict__ V,
    uint* __restrict__ P, float* __restrict__ O) {
  const int tid  = threadIdx.x;
  const int b    = blockIdx.x;     // 0..255
  const int jb   = b >> 2;
  const int part = b & 3;

  // zero O slice (2MB spread over 256 WGs)
  {
    float4 z = {0.f, 0.f, 0.f, 0.f};
    float4* op = (float4*)O;
#pragma unroll
    for (int it = 0; it < 2; ++it) op[b * 512 + it * NT + tid] = z;
  }

  // K 2-term f16 split -> swizzled planes (element (r,c): chunk=c/8,
  // uint off r*64 + ((chunk ^ (r&15))*4) + (c%8)/2); 2048 float4 per block.
  {
    const float4* gk = (const float4*)(K + (size_t)jb * BLK * DIM);
    uint* dst = P + (size_t)jb * PSTR;
#pragma unroll
    for (int it = 0; it < 2; ++it) {
      int f = part * 512 + it * NT + tid;   // float4 idx 0..2047
      int r = f >> 5, c4 = f & 31;
      float4 x = gk[f];
      float xs[4] = {x.x, x.y, x.z, x.w};
      UH4 uh, ur;
#pragma unroll
      for (int e = 0; e < 4; ++e) {
        float v = xs[e];
        _Float16 h = (_Float16)v;
        uh.h[e] = h;
        ur.h[e] = (_Float16)(v - (float)h);   // exact residual (Sterbenz)
      }
      uint off = (uint)r * 64u + (((uint)(c4 >> 1) ^ (uint)(r & 15)) << 2) +
                 (uint)((c4 & 1) << 1);
      *(uint2*)&dst[off]        = uh.u;
      *(uint2*)&dst[4096 + off] = ur.u;
    }
  }

  // Vt in PV B-frag linear order: 1024 fragments; frag idx = ch*128 + d,
  // 8 f16 = V[ch*8+j][d]. One frag/thread.
  {
    const float* gv = V + (size_t)jb * BLK * DIM;
    uint4* dv = (uint4*)(P + (size_t)jb * PSTR + 8192);
    int idx = part * 256 + tid;            // frag idx 0..1023
    int ch = idx >> 7, d = idx & 127;
    UH8 u;
#pragma unroll
    for (int j = 0; j < 8; ++j)
      u.v[j] = (_Float16)gv[(ch * 8 + j) * DIM + d];
    dv[idx] = u.u;
  }
}

__global__ __launch_bounds__(NT, 4) void eco_attn_kernel(
    const float* __restrict__ Q, const uint* __restrict__ P,
    float* __restrict__ O) {
  __shared__ __align__(16) uint sK[8192];   // 32 KB: Khi / Kr planes
  __shared__ __align__(16) uint sW[2048];   // 8 KB: 4 x (16 rows x 32 uints)

  const int tid  = threadIdx.x;
  const int ib   = blockIdx.y;
  const int jg   = blockIdx.x;
  const int lane = tid & 63;
  const int wv   = tid >> 6;
  const int quad = lane >> 4;   // 0..3
  const int l16  = lane & 15;
  const int q4   = quad << 2;

  uint* sWw = sW + wv * 512;    // this wave's weight rows (16 x 32 uints)

  // ---- Q fragments (B-operand): q-row = wv*16+l16, k = ks*32+quad*8+j ----
  f16x8 qh[4], qr[4];
  {
    const float* qp = Q + (size_t)(ib * BLK + wv * 16 + l16) * DIM + quad * 8;
#pragma unroll
    for (int ks = 0; ks < 4; ++ks) {
      float4 x0 = *(const float4*)(qp + ks * 32);
      float4 x1 = *(const float4*)(qp + ks * 32 + 4);
      float xs[8] = {x0.x, x0.y, x0.z, x0.w, x1.x, x1.y, x1.z, x1.w};
      f16x8 h8, r8;
#pragma unroll
      for (int e = 0; e < 8; ++e) {
        float v = xs[e];
        _Float16 h = (_Float16)v;
        h8[e] = h;
        r8[e] = (_Float16)(v - (float)h);
      }
      qh[ks] = h8; qr[ks] = r8;
    }
  }

  const f32x4 zf = {0.f, 0.f, 0.f, 0.f};
  f32x4 pv[8];
#pragma unroll
  for (int i = 0; i < 8; ++i) pv[i] = zf;

  // prologue: stage first K image (32KB = 8 x 16B per thread)
  {
    const uint* gsrc = P + (size_t)(jg * JPB) * PSTR;
#pragma unroll
    for (int it = 0; it < 8; ++it) {
      int idx = (it * NT + tid) << 2;
      gll16(gsrc + idx, sK + idx);
    }
  }

  for (int jj = 0; jj < JPB; ++jj) {
    const int jb = jg * JPB + jj;
    __syncthreads();  // B1: K image staged (vmcnt drained by barrier)

    // ---- QK^T, operand-swapped: A = K (from LDS), B = Q (resident) ----
    // C: col(l16) = Q-row (wv*16+l16), row(quad*4+reg) = K-row nt*16+quad*4+reg
    f32x4 ah[4], ar[4];
#pragma unroll
    for (int nt = 0; nt < 4; ++nt) { ah[nt] = zf; ar[nt] = zf; }
#pragma unroll
    for (int nt = 0; nt < 4; ++nt) {
      const int rB = nt * 16 + l16;      // K-row for the A-frag read
      const uint rowoff = (uint)rB * 64u;
      const uint swk = (uint)(rB & 15);
#pragma unroll
      for (int ks = 0; ks < 4; ++ks) {
        uint off = rowoff + ((((uint)(ks * 4 + quad)) ^ swk) << 2);
        f16x8 bh = *(const f16x8*)&sK[off];
        f16x8 br = *(const f16x8*)&sK[4096 + off];
        ah[nt] = MFMAH(bh, qh[ks], ah[nt]);
        ar[nt] = MFMAH(br, qh[ks], ar[nt]);
        ar[nt] = MFMAH(bh, qr[ks], ar[nt]);
      }
    }
    __syncthreads();  // B0: all waves done reading sK

    // ---- prefetch next K image (overlaps softmax + PV below) ----
    if (jj + 1 < JPB) {
      const uint* gsrc = P + (size_t)(jb + 1) * PSTR;
#pragma unroll
      for (int it = 0; it < 8; ++it) {
        int idx = (it * NT + tid) << 2;
        gll16(gsrc + idx, sK + idx);
      }
    }

    // ---- top-p softmax via max-extraction: lane owns Q-row wv*16+l16;
    //      element i (= nt*4+rg) is score at K-index nt*16 + q4 + rg ----
    {
      float e[16], w[16];
#pragma unroll
      for (int nt = 0; nt < 4; ++nt) {
        f32x4 s = ah[nt] + ar[nt];
#pragma unroll
        for (int rg = 0; rg < 4; ++rg) w[nt * 4 + rg] = s[rg];
      }
      // row max: local tree + cross-quad
      float mt[8];
#pragma unroll
      for (int i = 0; i < 8; ++i) mt[i] = fmaxf(w[i], w[i + 8]);
#pragma unroll
      for (int w2 = 4; w2 >= 1; w2 >>= 1)
#pragma unroll
        for (int i = 0; i < w2; ++i) mt[i] = fmaxf(mt[i], mt[i + w2]);
      float m = mt[0];
      m = fmaxf(m, __shfl_xor(m, 16, 64));
      m = fmaxf(m, __shfl_xor(m, 32, 64));
#pragma unroll
      for (int i = 0; i < 16; ++i) { w[i] = __expf(w[i] - m); e[i] = w[i]; }
      // row sum
      float st[8];
#pragma unroll
      for (int i = 0; i < 8; ++i) st[i] = w[i] + w[i + 8];
#pragma unroll
      for (int w2 = 4; w2 >= 1; w2 >>= 1)
#pragma unroll
        for (int i = 0; i < w2; ++i) st[i] += st[i + w2];
      float sr = st[0];
      sr += __shfl_xor(sr, 16, 64);
      sr += __shfl_xor(sr, 32, 64);
      const float T = THRESH * sr;

      // t = #extraction steps whose running (descending-sorted) sum < T.
      // 4 unrolled steps cover the common case (t <= 3); tail loop is rare.
      float R = 0.f;
      int c = 0;
      bool done = false;
      ext_step(w, R, c, done, T);
      ext_step(w, R, c, done, T);
      ext_step(w, R, c, done, T);
      ext_step(w, R, c, done, T);
      for (int s2 = 0; s2 < 60 && __any(!done); ++s2)
        ext_step(w, R, c, done, T);
      const int t = c;   // same value in all 4 lanes of the row

      // renormalize first-t (ORIGINAL K order; kidx = nt*16 + q4 + rg)
      float p = 0.f;
#pragma unroll
      for (int i = 0; i < 16; ++i) {
        int kidx = ((i >> 2) << 4) + q4 + (i & 3);
        p += (kidx < t) ? e[i] : 0.f;
      }
      p += __shfl_xor(p, 16, 64);
      p += __shfl_xor(p, 32, 64);
      const float rn = 1.0f / (p + EPSF);
      // emit f16 weights: row l16, 16 chunks of 4 f16; chunk c4 = nt*4+quad
      // at swizzled uint offset row*32 + ((c4 ^ row) << 1)
      uint* wrow = sWw + l16 * 32;
#pragma unroll
      for (int nt = 0; nt < 4; ++nt) {
        UH4 u;
#pragma unroll
        for (int rg = 0; rg < 4; ++rg) {
          int kidx = nt * 16 + q4 + rg;
          float wgt = (kidx < t) ? e[nt * 4 + rg] * rn : 0.f;
          u.h[rg] = (_Float16)wgt;
        }
        uint c4 = (uint)(nt * 4 + quad);
        *(uint2*)&wrow[(c4 ^ (uint)l16) << 1] = u.u;
      }
    }
    __builtin_amdgcn_wave_barrier();  // weight writes before A-frag reads

    // ---- PV: A = f16 weights (wave-private LDS), B = Vt-frag from global ----
    f16x8 wf[2];
#pragma unroll
    for (int ks2 = 0; ks2 < 2; ++ks2) {
      uint c0 = (uint)(ks2 * 8 + quad * 2);
      const uint* wrow = sWw + l16 * 32;
      uint2 lo = *(const uint2*)&wrow[(c0 ^ (uint)l16) << 1];
      uint2 hi = *(const uint2*)&wrow[((c0 + 1) ^ (uint)l16) << 1];
      UH8 u;
      u.u = make_uint4(lo.x, lo.y, hi.x, hi.y);
      wf[ks2] = u.v;
    }
    {
      const uint* gvt = P + (size_t)jb * PSTR + 8192;
#pragma unroll
      for (int nt2 = 0; nt2 < 8; ++nt2) {
#pragma unroll
        for (int ks2 = 0; ks2 < 2; ++ks2) {
          f16x8 vf = *(const f16x8*)&gvt[((uint)((ks2 * 4 + quad) * 128 +
                                                 nt2 * 16 + l16)) << 2];
          pv[nt2] = MFMAH(wf[ks2], vf, pv[nt2]);
        }
      }
    }
    __builtin_amdgcn_wave_barrier();  // PV weight reads before next-iter writes
  }

  // ---- epilogue: C-layout -> global atomicAdd over the 16 j-groups ----
#pragma unroll
  for (int nt2 = 0; nt2 < 8; ++nt2) {
    const int col  = nt2 * 16 + l16;
    const int row0 = ib * BLK + wv * 16 + quad * 4;
#pragma unroll
    for (int rg = 0; rg < 4; ++rg)
      atomicAdd(O + (size_t)(row0 + rg) * DIM + col, pv[nt2][rg]);
  }
}

extern "C" void kernel_launch(void* const* d_in, const int* in_sizes, int n_in,
                              void* d_out, int out_size, void* d_ws, size_t ws_size,
                              hipStream_t stream) {
  (void)in_sizes; (void)n_in; (void)ws_size; (void)out_size;
  const float* q = (const float*)d_in[0];
  const float* k = (const float*)d_in[1];
  const float* v = (const float*)d_in[2];
  float* out = (float*)d_out;
  uint* prep = (uint*)d_ws;   // 64 blocks x 48 KB = 3 MB

  eco_prep_kernel<<<dim3(NB * 4), dim3(NT), 0, stream>>>(k, v, prep, out);
  eco_attn_kernel<<<dim3(NJG, NB), dim3(NT), 0, stream>>>(q, prep, out);
}